// Round 3
// baseline (387.127 us; speedup 1.0000x reference)
//
#include <hip/hip_runtime.h>
#include <hip/hip_bf16.h>

// W8Linear: out[32,16384] = (x[32,4096] . W[16384,4096]^T) * scale[n] + bias[n]
// Harness dtype reality (forensically confirmed over rounds 0-2):
//   - x/scale/bias: fp16 inputs PROMOTED TO FLOAT32 buffers
//       (round-1: reading x as bf16 gave finite ~5.2e21 = the ±2^65 low-half
//        pattern of fp16->fp32 promoted bits; predicted 4e21, matched)
//   - weight: int32 buffer (268 MB -> memory-bound, floor ~43 us @6.3 TB/s)
//   - OUTPUT: fp16 is "else float*" per harness map -> d_out is FLOAT32
//       (round-2: bf16-packed writes gave absmax 558 ~= sqrt(2)*ref-max, the
//        pair-read signature; this round writes fp32)
// Pure-register MFMA (16x16x32 bf16), no LDS, no barriers.
// Wave = 16 channels x 32 tokens; block = 4 waves = 64 channels; grid = 256.

typedef __attribute__((ext_vector_type(4))) int    i32x4;
typedef __attribute__((ext_vector_type(4))) float  f32x4;
typedef __attribute__((ext_vector_type(8))) short  s16x8;
typedef __attribute__((ext_vector_type(8))) __bf16 bf16x8;

constexpr int K = 4096;
constexpr int N = 16384;

// fp32 -> bf16 round-to-nearest-even (inputs are finite; no NaN handling needed).
__device__ inline unsigned short f2bf_rne(float f) {
    unsigned u = __builtin_bit_cast(unsigned, f);
    u += 0x7FFF + ((u >> 16) & 1);
    return (unsigned short)(u >> 16);
}

// 8 int32 weights -> 8 bf16, exact (|w|<=127 fits bf16 mantissa; truncation lossless).
__device__ inline bf16x8 cvtW(i32x4 lo, i32x4 hi) {
    s16x8 r;
#pragma unroll
    for (int i = 0; i < 4; ++i) {
        r[i]     = (short)(__builtin_bit_cast(unsigned, (float)lo[i]) >> 16);
        r[i + 4] = (short)(__builtin_bit_cast(unsigned, (float)hi[i]) >> 16);
    }
    return __builtin_bit_cast(s16x8, r), __builtin_bit_cast(bf16x8, r);
}

// 8 fp32 x-values -> 8 bf16, RNE.
__device__ inline bf16x8 cvtX(f32x4 lo, f32x4 hi) {
    s16x8 r;
#pragma unroll
    for (int i = 0; i < 4; ++i) {
        r[i]     = (short)f2bf_rne(lo[i]);
        r[i + 4] = (short)f2bf_rne(hi[i]);
    }
    return __builtin_bit_cast(bf16x8, r);
}

__global__ __launch_bounds__(256, 1) void w8linear_kernel(
    const float* __restrict__ x,
    const int* __restrict__ w,
    const float* __restrict__ scale,
    const float* __restrict__ bias,
    float* __restrict__ out)
{
    const int lane = threadIdx.x & 63;
    const int wave = threadIdx.x >> 6;
    const int n16  = lane & 15;   // B col / D col / channel-within-16
    const int quad = lane >> 4;   // k-subblock for A/B, row-subblock for D

    const int c = blockIdx.x * 64 + wave * 16 + n16;   // output channel

    const int*   __restrict__ wrow  = w + (size_t)c * K;
    const float* __restrict__ xrow0 = x + (size_t)n16 * K;          // tokens 0..15
    const float* __restrict__ xrow1 = x + (size_t)(n16 + 16) * K;   // tokens 16..31

    f32x4 acc0 = {0.f, 0.f, 0.f, 0.f};
    f32x4 acc1 = {0.f, 0.f, 0.f, 0.f};

    // K-chunk = 128 (4 mfma k-steps of 32); double-buffered raw loads,
    // conversions deferred to compute so vmcnt waits stay one chunk behind.
    i32x4 bA[8], bB[8];
    f32x4 aA[16], aB[16];

    auto load_chunk = [&](int k0, i32x4* bb, f32x4* ax) {
#pragma unroll
        for (int s = 0; s < 4; ++s) {
            const int ks = k0 + 32 * s + quad * 8;
            bb[2 * s]     = *reinterpret_cast<const i32x4*>(wrow + ks);
            bb[2 * s + 1] = *reinterpret_cast<const i32x4*>(wrow + ks + 4);
            ax[4 * s]     = *reinterpret_cast<const f32x4*>(xrow0 + ks);
            ax[4 * s + 1] = *reinterpret_cast<const f32x4*>(xrow0 + ks + 4);
            ax[4 * s + 2] = *reinterpret_cast<const f32x4*>(xrow1 + ks);
            ax[4 * s + 3] = *reinterpret_cast<const f32x4*>(xrow1 + ks + 4);
        }
    };
    auto compute_chunk = [&](const i32x4* bb, const f32x4* ax) {
#pragma unroll
        for (int s = 0; s < 4; ++s) {
            bf16x8 bf = cvtW(bb[2 * s], bb[2 * s + 1]);
            bf16x8 a0 = cvtX(ax[4 * s], ax[4 * s + 1]);
            bf16x8 a1 = cvtX(ax[4 * s + 2], ax[4 * s + 3]);
            acc0 = __builtin_amdgcn_mfma_f32_16x16x32_bf16(a0, bf, acc0, 0, 0, 0);
            acc1 = __builtin_amdgcn_mfma_f32_16x16x32_bf16(a1, bf, acc1, 0, 0, 0);
        }
    };

    load_chunk(0, bA, aA);
#pragma unroll 1
    for (int k0 = 0; k0 < K; k0 += 256) {
        load_chunk(k0 + 128, bB, aB);
        compute_chunk(bA, aA);
        if (k0 + 256 < K) load_chunk(k0 + 256, bA, aA);
        compute_chunk(bB, aB);
    }

    // Epilogue: D layout col = lane&15, row = quad*4 + reg. Output is FLOAT32.
    const float sc = scale[c];
    const float bi = bias[c];
#pragma unroll
    for (int v = 0; v < 4; ++v) {
        const int row = quad * 4 + v;
        out[(size_t)row * N + c]        = acc0[v] * sc + bi;
        out[(size_t)(row + 16) * N + c] = acc1[v] * sc + bi;
    }
}

extern "C" void kernel_launch(void* const* d_in, const int* in_sizes, int n_in,
                              void* d_out, int out_size, void* d_ws, size_t ws_size,
                              hipStream_t stream) {
    const float* x     = (const float*)d_in[0];
    const int*   w     = (const int*)d_in[1];
    const float* scale = (const float*)d_in[2];
    const float* bias  = (const float*)d_in[3];
    float* out = (float*)d_out;

    dim3 grid(N / 64);   // 256 blocks
    dim3 block(256);     // 4 waves
    w8linear_kernel<<<grid, block, 0, stream>>>(x, w, scale, bias, out);
}